// Round 14
// baseline (59.884 us; speedup 1.0000x reference)
//
#include <hip/hip_runtime.h>
#include <hip/hip_bf16.h>
#include <math.h>

#define N_CELLS 8192
#define D_DIM 64
#define H_DIM 128
#define GRID_SZ 256
#define NBINS (GRID_SZ * GRID_SZ)
#define BUCKET_CAP 16

typedef short bf16x8 __attribute__((ext_vector_type(8)));
typedef float f32x4 __attribute__((ext_vector_type(4)));

static __device__ __forceinline__ short f2bf(float x) {
    __hip_bfloat16 b = __float2bfloat16(x);
    return __builtin_bit_cast(short, b);
}

// ---------------- K1: prep_fill — ONE dispatch:
//   block 0   : clear counts -> __syncthreads -> bin_fill (intra-block ordering)
//   blocks 1-32 : Wb pack/permute (gate-interleaved bf16)
//   blocks 33-40: W_out hi/lo split pack (transposed [d][h])
//   block 41  : W_role pad [16][128]
__global__ __launch_bounds__(1024) void prep_fill(const int* __restrict__ positions,
                                                  const float* __restrict__ Wih,
                                                  const float* __restrict__ Whh,
                                                  const float* __restrict__ W_out,
                                                  const float* __restrict__ W_role,
                                                  __hip_bfloat16* __restrict__ Wb,
                                                  __hip_bfloat16* __restrict__ Wohi,
                                                  __hip_bfloat16* __restrict__ Wolo,
                                                  __hip_bfloat16* __restrict__ Wr,
                                                  int* __restrict__ counts,
                                                  int* __restrict__ buckets) {
    int tid = threadIdx.x, b = blockIdx.x;
    if (b == 0) {
        int4* c4 = (int4*)counts;
        #pragma unroll
        for (int e = 0; e < 16; ++e) c4[e * 1024 + tid] = make_int4(0, 0, 0, 0);
        __threadfence();
        __syncthreads();                    // clears visible before any atomic below
        #pragma unroll
        for (int e = 0; e < 8; ++e) {
            int i = e * 1024 + tid;
            int p0 = positions[2 * i], p1 = positions[2 * i + 1];
            int bin = p0 * GRID_SZ + p1;
            int slot = atomicAdd(&counts[bin], 1);
            if (slot < BUCKET_CAP) buckets[bin * BUCKET_CAP + slot] = i;
        }
    } else if (b <= 32) {
        // Wb row g': group=g'>>6, c6=g'&63, gate=c6>>4, hl=c6&15; orig = gate*128+group*16+hl
        int idx4 = (b - 1) * 1024 + tid;    // 32768 float4 chunks
        int gp = idx4 >> 6, k4 = (idx4 & 63) << 2;
        int group = gp >> 6, c6 = gp & 63, gate = c6 >> 4, hl = c6 & 15;
        int orig = gate * 128 + group * 16 + hl;
        float4 v = (k4 < 128) ? *(const float4*)(Wih + orig * 128 + k4)
                              : *(const float4*)(Whh + orig * 128 + (k4 - 128));
        short4 o = make_short4(f2bf(v.x), f2bf(v.y), f2bf(v.z), f2bf(v.w));
        *(short4*)((short*)Wb + gp * 256 + k4) = o;
    } else if (b <= 40) {
        int u = (b - 33) * 1024 + tid;      // 8192: u = h*64 + d
        int hh = u >> 6, d = u & 63;
        float w = W_out[u];
        float whi = __bfloat162float(__float2bfloat16(w));
        Wohi[d * 128 + hh] = __float2bfloat16(whi);
        Wolo[d * 128 + hh] = __float2bfloat16(w - whi);
    } else {
        #pragma unroll
        for (int e = 0; e < 2; ++e) {       // 2048: r(16) x h(128), rows 3..15 zero
            int u = e * 1024 + tid;
            int r = u >> 7, hh = u & 127;
            float w = (r < 3) ? W_role[hh * 3 + r] : 0.0f;
            Wr[r * 128 + hh] = __float2bfloat16(w);
        }
    }
}

// ---------------- K2: build_xh — WAVE-PARALLEL gather (lane t probes stencil bin t) ----------
__global__ __launch_bounds__(256) void build_xh(const int* __restrict__ positions,
                                                const float* __restrict__ states,
                                                const float* __restrict__ h,
                                                const int* __restrict__ counts,
                                                const int* __restrict__ buckets,
                                                __hip_bfloat16* __restrict__ xh) {
    int wave = threadIdx.x >> 6;
    int lane = threadIdx.x & 63;
    int i = blockIdx.x * 4 + wave;   // one wave per cell
    int p0 = positions[2 * i], p1 = positions[2 * i + 1];

    // lane t -> stencil offset (da,db), t in [0,29)
    int t = lane;
    int da, db;
    if (t == 0)      { da = -3; db = 0; }
    else if (t < 6)  { da = -2; db = t - 3; }
    else if (t < 11) { da = -1; db = t - 8; }
    else if (t < 18) { da = 0;  db = t - 14; }
    else if (t < 23) { da = 1;  db = t - 20; }
    else if (t < 28) { da = 2;  db = t - 25; }
    else             { da = 3;  db = 0; }

    int q0 = p0 + da, q1 = p1 + db;
    bool ok = (lane < 29) && ((unsigned)q0 < GRID_SZ) && ((unsigned)q1 < GRID_SZ);
    int bin = q0 * GRID_SZ + q1;

    int cl = 0;
    int4 jv = make_int4(0, 0, 0, 0);
    if (ok) {
        cl = counts[bin];                                 // parallel across lanes
        jv = *(const int4*)(buckets + bin * BUCKET_CAP);  // independent -> same latency wave
        if (cl > BUCKET_CAP) cl = BUCKET_CAP;
    }

    unsigned long long act = __ballot(cl > 0);
    float acc = 0.0f;
    int cnt = 0;
    while (act) {
        int tb = __ffsll(act) - 1;
        act &= act - 1;
        int ct = __shfl(cl, tb);
        int j0 = __shfl(jv.x, tb), j1 = __shfl(jv.y, tb);
        int j2 = __shfl(jv.z, tb), j3 = __shfl(jv.w, tb);
        if (j0 != i)           { cnt++; acc += states[j0 * D_DIM + lane]; }
        if (ct > 1 && j1 != i) { cnt++; acc += states[j1 * D_DIM + lane]; }
        if (ct > 2 && j2 != i) { cnt++; acc += states[j2 * D_DIM + lane]; }
        if (ct > 3 && j3 != i) { cnt++; acc += states[j3 * D_DIM + lane]; }
        if (ct > 4) {                                      // rare (P ~ 1e-6)
            int bb = __shfl(bin, tb) * BUCKET_CAP;
            for (int s = 4; s < ct; ++s) {
                int j = buckets[bb + s];
                if (j != i) { cnt++; acc += states[j * D_DIM + lane]; }
            }
        }
    }
    float nbr = (cnt > 0) ? acc / (float)cnt : 0.0f;

    __hip_bfloat16* row = xh + (size_t)i * 256;
    row[lane]       = __float2bfloat16(states[i * D_DIM + lane]);
    row[64 + lane]  = __float2bfloat16(nbr);
    row[128 + lane] = __float2bfloat16(h[i * H_DIM + lane]);
    row[192 + lane] = __float2bfloat16(h[i * H_DIM + 64 + lane]);
}

// ---------------- K3: mega — double-buffered Bs pipeline + direct-reg A + LSTM + heads -------
// LDS: Bs0 64K @0 | Bs1 64K @64K | Hl 8K @128K.  Head weights overlay Bs0 during kc=3.
__global__ __launch_bounds__(512) void mega(const __hip_bfloat16* __restrict__ xh,
                                            const __hip_bfloat16* __restrict__ Wb,
                                            const float* __restrict__ bias,
                                            const float* __restrict__ c_in,
                                            const __hip_bfloat16* __restrict__ Wohi,
                                            const __hip_bfloat16* __restrict__ Wolo,
                                            const __hip_bfloat16* __restrict__ Wr,
                                            float* __restrict__ out) {
    __shared__ char smem[139264];          // 136 KB
    char* Bs0 = smem;
    char* Bs1 = smem + 65536;
    char* Hl  = smem + 131072;             // 32 x 256B
    char* Whi = smem;                      // overlay in Bs0 after kc2 retires
    char* Wlo = smem + 16384;
    char* Wrl = smem + 32768;

    const int tid  = threadIdx.x;
    const int lane = tid & 63;
    const int wid  = tid >> 6;
    const int wrow = wid >> 2, wcol = wid & 3;
    const int n0 = blockIdx.x * 32;

    const char* bG = (const char*)Wb;      // row stride 512B

    auto stageB = [&](int kcc, char* dst) {
        #pragma unroll
        for (int e = 0; e < 8; ++e) {      // 4096 x 16B = 64 KB
            int u = e * 512 + tid;
            int row = u >> 3, slot = (u & 7) << 4;
            __builtin_amdgcn_global_load_lds(
                (const __attribute__((address_space(1))) void*)(bG + (size_t)row * 512 + kcc * 128 + (slot ^ ((row & 7) << 4))),
                (__attribute__((address_space(3))) void*)(dst + row * 128 + slot), 16, 0, 0);
        }
    };

    // ---- prologue: issue Bs chunk 0; prefetch A-frags, c_in, bias into registers ----
    stageB(0, Bs0);

    const short* xr = (const short*)xh + (size_t)(n0 + wrow * 16 + (lane & 15)) * 256 + ((lane >> 4) << 3);
    bf16x8 av[8];
    #pragma unroll
    for (int z = 0; z < 8; ++z) av[z] = *(const bf16x8*)(xr + z * 32);   // K = z*32..z*32+31

    float cv[2][4];
    float bi[2], bff[2], bgg[2], boo[2];
    #pragma unroll
    for (int b = 0; b < 2; ++b) {
        int hg = (2 * wcol + b) * 16 + (lane & 15);
        bi[b]  = bias[hg];
        bff[b] = bias[128 + hg];
        bgg[b] = bias[256 + hg];
        boo[b] = bias[384 + hg];
        #pragma unroll
        for (int r = 0; r < 4; ++r) {
            int ml = wrow * 16 + ((lane >> 4) << 2) + r;
            cv[b][r] = c_in[(size_t)(n0 + ml) * H_DIM + hg];
        }
    }
    __syncthreads();                       // Bs0 staged (implicit vmcnt drain)

    // ---- K-loop: ping-pong Bs, stage(k+1) issued before MFMA(k), 1 barrier/chunk ----
    f32x4 acc[8] = {};                     // [ni] over 128 cols of this wave

    #pragma unroll
    for (int kc = 0; kc < 4; ++kc) {
        if (kc < 3) {
            stageB(kc + 1, (kc & 1) ? Bs0 : Bs1);
        } else {
            // stage head weights into retired Bs0 region (Bs0 last read in kc2)
            const char* hiG = (const char*)Wohi;
            const char* loG = (const char*)Wolo;
            const char* wrG = (const char*)Wr;
            #pragma unroll
            for (int e = 0; e < 2; ++e) {
                int u = e * 512 + tid;
                int row = u >> 4, slot = (u & 15) << 4;
                int src = row * 256 + (slot ^ ((row & 7) << 4));
                __builtin_amdgcn_global_load_lds(
                    (const __attribute__((address_space(1))) void*)(hiG + src),
                    (__attribute__((address_space(3))) void*)(Whi + row * 256 + slot), 16, 0, 0);
                __builtin_amdgcn_global_load_lds(
                    (const __attribute__((address_space(1))) void*)(loG + src),
                    (__attribute__((address_space(3))) void*)(Wlo + row * 256 + slot), 16, 0, 0);
            }
            if (tid < 256) {
                int row = tid >> 4, slot = (tid & 15) << 4;
                __builtin_amdgcn_global_load_lds(
                    (const __attribute__((address_space(1))) void*)(wrG + row * 256 + (slot ^ ((row & 7) << 4))),
                    (__attribute__((address_space(3))) void*)(Wrl + row * 256 + slot), 16, 0, 0);
            }
        }

        const char* B = (kc & 1) ? Bs1 : Bs0;
        #pragma unroll
        for (int ks = 0; ks < 2; ++ks) {
            int kb = ks * 64 + ((lane >> 4) << 4);
            #pragma unroll
            for (int ni = 0; ni < 8; ++ni) {
                int brow = wcol * 128 + ni * 16 + (lane & 15);
                bf16x8 bv = *(const bf16x8*)(B + brow * 128 + (kb ^ ((brow & 7) << 4)));
                acc[ni] = __builtin_amdgcn_mfma_f32_16x16x32_bf16(av[kc * 2 + ks], bv, acc[ni], 0, 0, 0);
            }
        }
        __syncthreads();                   // drains stage issued this iter; orders buffer reuse
    }

    // ---- LSTM pointwise in-register; h -> LDS (bf16, swizzled) ----
    #pragma unroll
    for (int b = 0; b < 2; ++b) {
        int hg = (2 * wcol + b) * 16 + (lane & 15);
        #pragma unroll
        for (int r = 0; r < 4; ++r) {
            int ml = wrow * 16 + ((lane >> 4) << 2) + r;
            float ig = acc[b * 4 + 0][r] + bi[b];
            float fg = acc[b * 4 + 1][r] + bff[b];
            float gg = acc[b * 4 + 2][r] + bgg[b];
            float og = acc[b * 4 + 3][r] + boo[b];
            float si = 1.0f / (1.0f + expf(-ig));
            float sf = 1.0f / (1.0f + expf(-fg));
            float so = 1.0f / (1.0f + expf(-og));
            float hn = so * tanhf(sf * cv[b][r] + si * tanhf(gg));
            *(short*)(Hl + ml * 256 + ((hg * 2) ^ ((ml & 7) << 4))) = f2bf(hn);
        }
    }
    __syncthreads();

    // ---- head GEMMs: out = h @ W_out (hi+lo), roleT = Wr @ h^T ----
    const int rb = wid >> 2, db2 = wid & 3;
    f32x4 oacc = {};
    f32x4 racc = {};
    #pragma unroll
    for (int ks = 0; ks < 4; ++ks) {       // K = 128
        int kb = ks * 64 + ((lane >> 4) << 4);
        int hrow = rb * 16 + (lane & 15);
        bf16x8 hv = *(const bf16x8*)(Hl + hrow * 256 + (kb ^ ((hrow & 7) << 4)));
        int drow = db2 * 16 + (lane & 15);
        int woff = drow * 256 + (kb ^ ((drow & 7) << 4));
        bf16x8 whi = *(const bf16x8*)(Whi + woff);
        bf16x8 wlo = *(const bf16x8*)(Wlo + woff);
        oacc = __builtin_amdgcn_mfma_f32_16x16x32_bf16(hv, whi, oacc, 0, 0, 0);
        oacc = __builtin_amdgcn_mfma_f32_16x16x32_bf16(hv, wlo, oacc, 0, 0, 0);
        if (db2 == 3) {
            int rrow = lane & 15;
            bf16x8 wr = *(const bf16x8*)(Wrl + rrow * 256 + (kb ^ ((rrow & 7) << 4)));
            racc = __builtin_amdgcn_mfma_f32_16x16x32_bf16(wr, hv, racc, 0, 0, 0);
        }
    }
    #pragma unroll
    for (int r = 0; r < 4; ++r) {
        int m = n0 + rb * 16 + ((lane >> 4) << 2) + r;
        out[(size_t)m * D_DIM + db2 * 16 + (lane & 15)] = oacc[r];
    }
    if (db2 == 3 && lane < 16) {
        int m = n0 + rb * 16 + lane;
        float l0 = racc[0], l1 = racc[1], l2 = racc[2];
        float mx = fmaxf(l0, fmaxf(l1, l2));
        float e0 = expf(l0 - mx), e1 = expf(l1 - mx), e2 = expf(l2 - mx);
        float s = e0 + e1 + e2;
        float* ro = out + (size_t)N_CELLS * D_DIM + (size_t)m * 3;
        ro[0] = e0 / s; ro[1] = e1 / s; ro[2] = e2 / s;
    }
}

// ---------------- host launcher: 3 dispatches ----------------
extern "C" void kernel_launch(void* const* d_in, const int* in_sizes, int n_in,
                              void* d_out, int out_size, void* d_ws, size_t ws_size,
                              hipStream_t stream) {
    const int*   positions = (const int*)d_in[0];
    const float* states    = (const float*)d_in[1];
    const float* h         = (const float*)d_in[2];
    const float* c         = (const float*)d_in[3];
    const float* Wih       = (const float*)d_in[4];
    const float* Whh       = (const float*)d_in[5];
    const float* bias      = (const float*)d_in[6];
    const float* Wout      = (const float*)d_in[7];
    const float* Wrole     = (const float*)d_in[8];
    float* out             = (float*)d_out;

    char* ws = (char*)d_ws;
    int*            counts  = (int*)ws;                          // 256 KB @ 0
    int*            buckets = (int*)(ws + 262144);               // 4 MB
    __hip_bfloat16* xh      = (__hip_bfloat16*)(ws + 4456448);   // 4 MB   [8192,256] bf16
    __hip_bfloat16* Wb      = (__hip_bfloat16*)(ws + 8650752);   // 256 KB [512,256] bf16
    __hip_bfloat16* Wohi    = (__hip_bfloat16*)(ws + 8912896);   // 16 KB  [64,128] bf16
    __hip_bfloat16* Wolo    = (__hip_bfloat16*)(ws + 8929280);   // 16 KB
    __hip_bfloat16* Wr      = (__hip_bfloat16*)(ws + 8945664);   // 4 KB   [16,128] bf16

    prep_fill<<<42, 1024, 0, stream>>>(positions, Wih, Whh, Wout, Wrole,
                                       Wb, Wohi, Wolo, Wr, counts, buckets);
    build_xh<<<N_CELLS / 4, 256, 0, stream>>>(positions, states, h, counts, buckets, xh);
    mega<<<256, 512, 0, stream>>>(xh, Wb, bias, c, Wohi, Wolo, Wr, out);
}

// Round 15
// 34.370 us; speedup vs baseline: 1.7423x; 1.7423x over previous
//
#include <hip/hip_runtime.h>
#include <hip/hip_bf16.h>
#include <math.h>

#define N_CELLS 8192
#define D_DIM 64
#define H_DIM 128
#define GRID_SZ 256
#define NBINS (GRID_SZ * GRID_SZ)
#define BUCKET_CAP 16

typedef short bf16x8 __attribute__((ext_vector_type(8)));
typedef float f32x4 __attribute__((ext_vector_type(4)));

static __device__ __forceinline__ short f2bf(float x) {
    __hip_bfloat16 b = __float2bfloat16(x);
    return __builtin_bit_cast(short, b);
}

// ---------------- K1: prep — Wb pack (0..127) | clear counts (128..191) |
//                  W_out hi/lo pack transposed (192..223) | W_role pad (224) ----------------
__global__ __launch_bounds__(256) void prep(const float* __restrict__ Wih,
                                            const float* __restrict__ Whh,
                                            const float* __restrict__ W_out,
                                            const float* __restrict__ W_role,
                                            __hip_bfloat16* __restrict__ Wb,
                                            __hip_bfloat16* __restrict__ Wohi,
                                            __hip_bfloat16* __restrict__ Wolo,
                                            __hip_bfloat16* __restrict__ Wr,
                                            int4* __restrict__ counts4) {
    int tid = threadIdx.x, b = blockIdx.x;
    if (b < 128) {
        // Wb row g': group=g'>>6, c6=g'&63, gate=c6>>4, hl=c6&15; orig = gate*128+group*16+hl
        int idx4 = b * 256 + tid;   // 32768 float4 chunks
        int gp = idx4 >> 6, k4 = (idx4 & 63) << 2;
        int group = gp >> 6, c6 = gp & 63, gate = c6 >> 4, hl = c6 & 15;
        int orig = gate * 128 + group * 16 + hl;
        float4 v = (k4 < 128) ? *(const float4*)(Wih + orig * 128 + k4)
                              : *(const float4*)(Whh + orig * 128 + (k4 - 128));
        short4 o = make_short4(f2bf(v.x), f2bf(v.y), f2bf(v.z), f2bf(v.w));
        *(short4*)((short*)Wb + gp * 256 + k4) = o;
    } else if (b < 192) {
        counts4[(b - 128) * 256 + tid] = make_int4(0, 0, 0, 0);
    } else if (b < 224) {
        int u = (b - 192) * 256 + tid;       // 8192: u = h*64 + d
        int hh = u >> 6, d = u & 63;
        float w = W_out[u];
        float whi = __bfloat162float(__float2bfloat16(w));
        Wohi[d * 128 + hh] = __float2bfloat16(whi);
        Wolo[d * 128 + hh] = __float2bfloat16(w - whi);
    } else {
        #pragma unroll
        for (int e = 0; e < 8; ++e) {        // 2048: r(16) x h(128), rows 3..15 zero
            int u = e * 256 + tid;
            int r = u >> 7, hh = u & 127;
            float w = (r < 3) ? W_role[hh * 3 + r] : 0.0f;
            Wr[r * 128 + hh] = __float2bfloat16(w);
        }
    }
}

// ---------------- K2: fill spatial-hash buckets ----------------
__global__ __launch_bounds__(256) void bin_fill(const int* __restrict__ positions,
                                                int* __restrict__ counts,
                                                int* __restrict__ buckets) {
    int i = blockIdx.x * 256 + threadIdx.x;
    if (i >= N_CELLS) return;
    int p0 = positions[2 * i], p1 = positions[2 * i + 1];
    int bin = p0 * GRID_SZ + p1;
    int slot = atomicAdd(&counts[bin], 1);
    if (slot < BUCKET_CAP) buckets[bin * BUCKET_CAP + slot] = i;
}

// ---------------- K3: build_xh — WAVE-PARALLEL gather (lane t probes stencil bin t) ----------
__global__ __launch_bounds__(256) void build_xh(const int* __restrict__ positions,
                                                const float* __restrict__ states,
                                                const float* __restrict__ h,
                                                const int* __restrict__ counts,
                                                const int* __restrict__ buckets,
                                                __hip_bfloat16* __restrict__ xh) {
    int wave = threadIdx.x >> 6;
    int lane = threadIdx.x & 63;
    int i = blockIdx.x * 4 + wave;   // one wave per cell
    int p0 = positions[2 * i], p1 = positions[2 * i + 1];

    // lane t -> stencil offset (da,db), t in [0,29)
    int t = lane;
    int da, db;
    if (t == 0)      { da = -3; db = 0; }
    else if (t < 6)  { da = -2; db = t - 3; }
    else if (t < 11) { da = -1; db = t - 8; }
    else if (t < 18) { da = 0;  db = t - 14; }
    else if (t < 23) { da = 1;  db = t - 20; }
    else if (t < 28) { da = 2;  db = t - 25; }
    else             { da = 3;  db = 0; }

    int q0 = p0 + da, q1 = p1 + db;
    bool ok = (lane < 29) && ((unsigned)q0 < GRID_SZ) && ((unsigned)q1 < GRID_SZ);
    int bin = q0 * GRID_SZ + q1;

    int cl = 0;
    int4 jv = make_int4(0, 0, 0, 0);
    if (ok) {
        cl = counts[bin];                                 // parallel across lanes
        jv = *(const int4*)(buckets + bin * BUCKET_CAP);  // independent -> same latency wave
        if (cl > BUCKET_CAP) cl = BUCKET_CAP;
    }

    unsigned long long act = __ballot(cl > 0);
    float acc = 0.0f;
    int cnt = 0;
    while (act) {
        int tb = __ffsll(act) - 1;
        act &= act - 1;
        int ct = __shfl(cl, tb);
        int j0 = __shfl(jv.x, tb), j1 = __shfl(jv.y, tb);
        int j2 = __shfl(jv.z, tb), j3 = __shfl(jv.w, tb);
        if (j0 != i)           { cnt++; acc += states[j0 * D_DIM + lane]; }
        if (ct > 1 && j1 != i) { cnt++; acc += states[j1 * D_DIM + lane]; }
        if (ct > 2 && j2 != i) { cnt++; acc += states[j2 * D_DIM + lane]; }
        if (ct > 3 && j3 != i) { cnt++; acc += states[j3 * D_DIM + lane]; }
        if (ct > 4) {                                      // rare (P ~ 1e-6)
            int bb = __shfl(bin, tb) * BUCKET_CAP;
            for (int s = 4; s < ct; ++s) {
                int j = buckets[bb + s];
                if (j != i) { cnt++; acc += states[j * D_DIM + lane]; }
            }
        }
    }
    float nbr = (cnt > 0) ? acc / (float)cnt : 0.0f;

    __hip_bfloat16* row = xh + (size_t)i * 256;
    row[lane]       = __float2bfloat16(states[i * D_DIM + lane]);
    row[64 + lane]  = __float2bfloat16(nbr);
    row[128 + lane] = __float2bfloat16(h[i * H_DIM + lane]);
    row[192 + lane] = __float2bfloat16(h[i * H_DIM + 64 + lane]);
}

// ---------------- K4: mega — 72KB LDS, 2 blocks/CU: single Bs buffer + direct-reg A ----------
// Inter-block TLP hides barrier/vmcnt drains (r13 showed intra-block pipelining is neutral).
// LDS: Bs 64K @0 | Hl 8K @64K. Head weights overlay retired Bs region after the GEMM.
__global__ __launch_bounds__(512, 4) void mega(const __hip_bfloat16* __restrict__ xh,
                                               const __hip_bfloat16* __restrict__ Wb,
                                               const float* __restrict__ bias,
                                               const float* __restrict__ c_in,
                                               const __hip_bfloat16* __restrict__ Wohi,
                                               const __hip_bfloat16* __restrict__ Wolo,
                                               const __hip_bfloat16* __restrict__ Wr,
                                               float* __restrict__ out) {
    __shared__ char smem[73728];           // 72 KB -> 2 blocks/CU
    char* Bs  = smem;                      // 512 x 128B per kc chunk
    char* Hl  = smem + 65536;              // 32 x 256B
    char* Whi = smem;                      // overlay in Bs after GEMM
    char* Wlo = smem + 16384;
    char* Wrl = smem + 32768;

    const int tid  = threadIdx.x;
    const int lane = tid & 63;
    const int wid  = tid >> 6;
    const int wrow = wid >> 2, wcol = wid & 3;
    const int n0 = blockIdx.x * 32;

    const char* bG = (const char*)Wb;      // row stride 512B

    auto stageB = [&](int kcc) {
        #pragma unroll
        for (int e = 0; e < 8; ++e) {      // 4096 x 16B = 64 KB
            int u = e * 512 + tid;
            int row = u >> 3, slot = (u & 7) << 4;
            __builtin_amdgcn_global_load_lds(
                (const __attribute__((address_space(1))) void*)(bG + (size_t)row * 512 + kcc * 128 + (slot ^ ((row & 7) << 4))),
                (__attribute__((address_space(3))) void*)(Bs + row * 128 + slot), 16, 0, 0);
        }
    };

    // ---- prologue: issue Bs chunk 0; prefetch A-frags, c_in, bias into registers ----
    stageB(0);

    const short* xr = (const short*)xh + (size_t)(n0 + wrow * 16 + (lane & 15)) * 256 + ((lane >> 4) << 3);
    bf16x8 av[8];
    #pragma unroll
    for (int z = 0; z < 8; ++z) av[z] = *(const bf16x8*)(xr + z * 32);   // K = z*32..z*32+31

    float cv[2][4];
    float bi[2], bff[2], bgg[2], boo[2];
    #pragma unroll
    for (int b = 0; b < 2; ++b) {
        int hg = (2 * wcol + b) * 16 + (lane & 15);
        bi[b]  = bias[hg];
        bff[b] = bias[128 + hg];
        bgg[b] = bias[256 + hg];
        boo[b] = bias[384 + hg];
        #pragma unroll
        for (int r = 0; r < 4; ++r) {
            int ml = wrow * 16 + ((lane >> 4) << 2) + r;
            cv[b][r] = c_in[(size_t)(n0 + ml) * H_DIM + hg];
        }
    }
    __syncthreads();                       // Bs chunk 0 staged

    // ---- K-loop: single buffer, MFMA -> sync -> stage(k+1) -> sync ----
    f32x4 acc[8] = {};                     // [ni] over 128 cols of this wave

    #pragma unroll
    for (int kc = 0; kc < 4; ++kc) {
        #pragma unroll
        for (int ks = 0; ks < 2; ++ks) {
            int kb = ks * 64 + ((lane >> 4) << 4);
            #pragma unroll
            for (int ni = 0; ni < 8; ++ni) {
                int brow = wcol * 128 + ni * 16 + (lane & 15);
                bf16x8 bv = *(const bf16x8*)(Bs + brow * 128 + (kb ^ ((brow & 7) << 4)));
                acc[ni] = __builtin_amdgcn_mfma_f32_16x16x32_bf16(av[kc * 2 + ks], bv, acc[ni], 0, 0, 0);
            }
        }
        __syncthreads();                   // all waves done reading Bs chunk kc
        if (kc < 3) {
            stageB(kc + 1);
            __syncthreads();               // staged chunk kc+1 visible
        }
    }

    // ---- stage head weights into retired Bs region; LSTM VALU overlaps the stage latency ----
    {
        const char* hiG = (const char*)Wohi;
        const char* loG = (const char*)Wolo;
        const char* wrG = (const char*)Wr;
        #pragma unroll
        for (int e = 0; e < 2; ++e) {
            int u = e * 512 + tid;
            int row = u >> 4, slot = (u & 15) << 4;
            int src = row * 256 + (slot ^ ((row & 7) << 4));
            __builtin_amdgcn_global_load_lds(
                (const __attribute__((address_space(1))) void*)(hiG + src),
                (__attribute__((address_space(3))) void*)(Whi + row * 256 + slot), 16, 0, 0);
            __builtin_amdgcn_global_load_lds(
                (const __attribute__((address_space(1))) void*)(loG + src),
                (__attribute__((address_space(3))) void*)(Wlo + row * 256 + slot), 16, 0, 0);
        }
        if (tid < 256) {
            int row = tid >> 4, slot = (tid & 15) << 4;
            __builtin_amdgcn_global_load_lds(
                (const __attribute__((address_space(1))) void*)(wrG + row * 256 + (slot ^ ((row & 7) << 4))),
                (__attribute__((address_space(3))) void*)(Wrl + row * 256 + slot), 16, 0, 0);
        }
    }

    // ---- LSTM pointwise in-register; h -> LDS (bf16, swizzled; Hl disjoint from overlay) ----
    #pragma unroll
    for (int b = 0; b < 2; ++b) {
        int hg = (2 * wcol + b) * 16 + (lane & 15);
        #pragma unroll
        for (int r = 0; r < 4; ++r) {
            int ml = wrow * 16 + ((lane >> 4) << 2) + r;
            float ig = acc[b * 4 + 0][r] + bi[b];
            float fg = acc[b * 4 + 1][r] + bff[b];
            float gg = acc[b * 4 + 2][r] + bgg[b];
            float og = acc[b * 4 + 3][r] + boo[b];
            float si = 1.0f / (1.0f + expf(-ig));
            float sf = 1.0f / (1.0f + expf(-fg));
            float so = 1.0f / (1.0f + expf(-og));
            float hn = so * tanhf(sf * cv[b][r] + si * tanhf(gg));
            *(short*)(Hl + ml * 256 + ((hg * 2) ^ ((ml & 7) << 4))) = f2bf(hn);
        }
    }
    __syncthreads();                       // drains head stage + Hl writes

    // ---- head GEMMs: out = h @ W_out (hi+lo), roleT = Wr @ h^T ----
    const int rb = wid >> 2, db2 = wid & 3;
    f32x4 oacc = {};
    f32x4 racc = {};
    #pragma unroll
    for (int ks = 0; ks < 4; ++ks) {       // K = 128
        int kb = ks * 64 + ((lane >> 4) << 4);
        int hrow = rb * 16 + (lane & 15);
        bf16x8 hv = *(const bf16x8*)(Hl + hrow * 256 + (kb ^ ((hrow & 7) << 4)));
        int drow = db2 * 16 + (lane & 15);
        int woff = drow * 256 + (kb ^ ((drow & 7) << 4));
        bf16x8 whi = *(const bf16x8*)(Whi + woff);
        bf16x8 wlo = *(const bf16x8*)(Wlo + woff);
        oacc = __builtin_amdgcn_mfma_f32_16x16x32_bf16(hv, whi, oacc, 0, 0, 0);
        oacc = __builtin_amdgcn_mfma_f32_16x16x32_bf16(hv, wlo, oacc, 0, 0, 0);
        if (db2 == 3) {
            int rrow = lane & 15;
            bf16x8 wr = *(const bf16x8*)(Wrl + rrow * 256 + (kb ^ ((rrow & 7) << 4)));
            racc = __builtin_amdgcn_mfma_f32_16x16x32_bf16(wr, hv, racc, 0, 0, 0);
        }
    }
    #pragma unroll
    for (int r = 0; r < 4; ++r) {
        int m = n0 + rb * 16 + ((lane >> 4) << 2) + r;
        out[(size_t)m * D_DIM + db2 * 16 + (lane & 15)] = oacc[r];
    }
    if (db2 == 3 && lane < 16) {
        int m = n0 + rb * 16 + lane;
        float l0 = racc[0], l1 = racc[1], l2 = racc[2];
        float mx = fmaxf(l0, fmaxf(l1, l2));
        float e0 = expf(l0 - mx), e1 = expf(l1 - mx), e2 = expf(l2 - mx);
        float s = e0 + e1 + e2;
        float* ro = out + (size_t)N_CELLS * D_DIM + (size_t)m * 3;
        ro[0] = e0 / s; ro[1] = e1 / s; ro[2] = e2 / s;
    }
}

// ---------------- host launcher: 4 dispatches ----------------
extern "C" void kernel_launch(void* const* d_in, const int* in_sizes, int n_in,
                              void* d_out, int out_size, void* d_ws, size_t ws_size,
                              hipStream_t stream) {
    const int*   positions = (const int*)d_in[0];
    const float* states    = (const float*)d_in[1];
    const float* h         = (const float*)d_in[2];
    const float* c         = (const float*)d_in[3];
    const float* Wih       = (const float*)d_in[4];
    const float* Whh       = (const float*)d_in[5];
    const float* bias      = (const float*)d_in[6];
    const float* Wout      = (const float*)d_in[7];
    const float* Wrole     = (const float*)d_in[8];
    float* out             = (float*)d_out;

    char* ws = (char*)d_ws;
    int*            counts  = (int*)ws;                          // 256 KB @ 0
    int*            buckets = (int*)(ws + 262144);               // 4 MB
    __hip_bfloat16* xh      = (__hip_bfloat16*)(ws + 4456448);   // 4 MB   [8192,256] bf16
    __hip_bfloat16* Wb      = (__hip_bfloat16*)(ws + 8650752);   // 256 KB [512,256] bf16
    __hip_bfloat16* Wohi    = (__hip_bfloat16*)(ws + 8912896);   // 16 KB  [64,128] bf16
    __hip_bfloat16* Wolo    = (__hip_bfloat16*)(ws + 8929280);   // 16 KB
    __hip_bfloat16* Wr      = (__hip_bfloat16*)(ws + 8945664);   // 4 KB   [16,128] bf16

    prep<<<225, 256, 0, stream>>>(Wih, Whh, Wout, Wrole, Wb, Wohi, Wolo, Wr, (int4*)counts);
    bin_fill<<<N_CELLS / 256, 256, 0, stream>>>(positions, counts, buckets);
    build_xh<<<N_CELLS / 4, 256, 0, stream>>>(positions, states, h, counts, buckets, xh);
    mega<<<256, 512, 0, stream>>>(xh, Wb, bias, c, Wohi, Wolo, Wr, out);
}

// Round 16
// 34.009 us; speedup vs baseline: 1.7608x; 1.0106x over previous
//
#include <hip/hip_runtime.h>
#include <hip/hip_bf16.h>
#include <math.h>

#define N_CELLS 8192
#define D_DIM 64
#define H_DIM 128
#define GRID_SZ 256
#define NBINS (GRID_SZ * GRID_SZ)
#define BUCKET_CAP 16

typedef short bf16x8 __attribute__((ext_vector_type(8)));
typedef float f32x4 __attribute__((ext_vector_type(4)));

static __device__ __forceinline__ short f2bf(float x) {
    __hip_bfloat16 b = __float2bfloat16(x);
    return __builtin_bit_cast(short, b);
}

// ---------------- K1: clear bin counts ONLY (minimal critical-path dispatch) ----------------
__global__ __launch_bounds__(256) void clear_counts(int4* __restrict__ counts4) {
    counts4[blockIdx.x * 256 + threadIdx.x] = make_int4(0, 0, 0, 0);
}

// ---------------- K2: fill_pack — bin_fill (blocks 0..31) co-scheduled with weight packing:
//   blocks 32..159 : Wb pack/permute | 160..191 : W_out hi/lo | 192 : W_role pad -------------
__global__ __launch_bounds__(256) void fill_pack(const int* __restrict__ positions,
                                                 const float* __restrict__ Wih,
                                                 const float* __restrict__ Whh,
                                                 const float* __restrict__ W_out,
                                                 const float* __restrict__ W_role,
                                                 __hip_bfloat16* __restrict__ Wb,
                                                 __hip_bfloat16* __restrict__ Wohi,
                                                 __hip_bfloat16* __restrict__ Wolo,
                                                 __hip_bfloat16* __restrict__ Wr,
                                                 int* __restrict__ counts,
                                                 int* __restrict__ buckets) {
    int tid = threadIdx.x, b = blockIdx.x;
    if (b < 32) {
        int i = b * 256 + tid;               // 8192 cells, one atomic each (full TLP)
        int p0 = positions[2 * i], p1 = positions[2 * i + 1];
        int bin = p0 * GRID_SZ + p1;
        int slot = atomicAdd(&counts[bin], 1);
        if (slot < BUCKET_CAP) buckets[bin * BUCKET_CAP + slot] = i;
    } else if (b < 160) {
        // Wb row g': group=g'>>6, c6=g'&63, gate=c6>>4, hl=c6&15; orig = gate*128+group*16+hl
        int idx4 = (b - 32) * 256 + tid;     // 32768 float4 chunks
        int gp = idx4 >> 6, k4 = (idx4 & 63) << 2;
        int group = gp >> 6, c6 = gp & 63, gate = c6 >> 4, hl = c6 & 15;
        int orig = gate * 128 + group * 16 + hl;
        float4 v = (k4 < 128) ? *(const float4*)(Wih + orig * 128 + k4)
                              : *(const float4*)(Whh + orig * 128 + (k4 - 128));
        short4 o = make_short4(f2bf(v.x), f2bf(v.y), f2bf(v.z), f2bf(v.w));
        *(short4*)((short*)Wb + gp * 256 + k4) = o;
    } else if (b < 192) {
        int u = (b - 160) * 256 + tid;       // 8192: u = h*64 + d
        int hh = u >> 6, d = u & 63;
        float w = W_out[u];
        float whi = __bfloat162float(__float2bfloat16(w));
        Wohi[d * 128 + hh] = __float2bfloat16(whi);
        Wolo[d * 128 + hh] = __float2bfloat16(w - whi);
    } else {
        #pragma unroll
        for (int e = 0; e < 8; ++e) {        // 2048: r(16) x h(128), rows 3..15 zero
            int u = e * 256 + tid;
            int r = u >> 7, hh = u & 127;
            float w = (r < 3) ? W_role[hh * 3 + r] : 0.0f;
            Wr[r * 128 + hh] = __float2bfloat16(w);
        }
    }
}

// ---------------- K3: build_xh — WAVE-PARALLEL gather (lane t probes stencil bin t) ----------
__global__ __launch_bounds__(256) void build_xh(const int* __restrict__ positions,
                                                const float* __restrict__ states,
                                                const float* __restrict__ h,
                                                const int* __restrict__ counts,
                                                const int* __restrict__ buckets,
                                                __hip_bfloat16* __restrict__ xh) {
    int wave = threadIdx.x >> 6;
    int lane = threadIdx.x & 63;
    int i = blockIdx.x * 4 + wave;   // one wave per cell
    int p0 = positions[2 * i], p1 = positions[2 * i + 1];

    // lane t -> stencil offset (da,db), t in [0,29)
    int t = lane;
    int da, db;
    if (t == 0)      { da = -3; db = 0; }
    else if (t < 6)  { da = -2; db = t - 3; }
    else if (t < 11) { da = -1; db = t - 8; }
    else if (t < 18) { da = 0;  db = t - 14; }
    else if (t < 23) { da = 1;  db = t - 20; }
    else if (t < 28) { da = 2;  db = t - 25; }
    else             { da = 3;  db = 0; }

    int q0 = p0 + da, q1 = p1 + db;
    bool ok = (lane < 29) && ((unsigned)q0 < GRID_SZ) && ((unsigned)q1 < GRID_SZ);
    int bin = q0 * GRID_SZ + q1;

    int cl = 0;
    int4 jv = make_int4(0, 0, 0, 0);
    if (ok) {
        cl = counts[bin];                                 // parallel across lanes
        jv = *(const int4*)(buckets + bin * BUCKET_CAP);  // independent -> same latency wave
        if (cl > BUCKET_CAP) cl = BUCKET_CAP;
    }

    unsigned long long act = __ballot(cl > 0);
    float acc = 0.0f;
    int cnt = 0;
    while (act) {
        int tb = __ffsll(act) - 1;
        act &= act - 1;
        int ct = __shfl(cl, tb);
        int j0 = __shfl(jv.x, tb), j1 = __shfl(jv.y, tb);
        int j2 = __shfl(jv.z, tb), j3 = __shfl(jv.w, tb);
        if (j0 != i)           { cnt++; acc += states[j0 * D_DIM + lane]; }
        if (ct > 1 && j1 != i) { cnt++; acc += states[j1 * D_DIM + lane]; }
        if (ct > 2 && j2 != i) { cnt++; acc += states[j2 * D_DIM + lane]; }
        if (ct > 3 && j3 != i) { cnt++; acc += states[j3 * D_DIM + lane]; }
        if (ct > 4) {                                      // rare (P ~ 1e-6)
            int bb = __shfl(bin, tb) * BUCKET_CAP;
            for (int s = 4; s < ct; ++s) {
                int j = buckets[bb + s];
                if (j != i) { cnt++; acc += states[j * D_DIM + lane]; }
            }
        }
    }
    float nbr = (cnt > 0) ? acc / (float)cnt : 0.0f;

    __hip_bfloat16* row = xh + (size_t)i * 256;
    row[lane]       = __float2bfloat16(states[i * D_DIM + lane]);
    row[64 + lane]  = __float2bfloat16(nbr);
    row[128 + lane] = __float2bfloat16(h[i * H_DIM + lane]);
    row[192 + lane] = __float2bfloat16(h[i * H_DIM + 64 + lane]);
}

// ---------------- K4: mega — double-buffered Bs pipeline + direct-reg A + LSTM + heads -------
// (r13 structure: best-known at 33.607us)
__global__ __launch_bounds__(512) void mega(const __hip_bfloat16* __restrict__ xh,
                                            const __hip_bfloat16* __restrict__ Wb,
                                            const float* __restrict__ bias,
                                            const float* __restrict__ c_in,
                                            const __hip_bfloat16* __restrict__ Wohi,
                                            const __hip_bfloat16* __restrict__ Wolo,
                                            const __hip_bfloat16* __restrict__ Wr,
                                            float* __restrict__ out) {
    __shared__ char smem[139264];          // 136 KB
    char* Bs0 = smem;
    char* Bs1 = smem + 65536;
    char* Hl  = smem + 131072;             // 32 x 256B
    char* Whi = smem;                      // overlay in Bs0 after kc2 retires
    char* Wlo = smem + 16384;
    char* Wrl = smem + 32768;

    const int tid  = threadIdx.x;
    const int lane = tid & 63;
    const int wid  = tid >> 6;
    const int wrow = wid >> 2, wcol = wid & 3;
    const int n0 = blockIdx.x * 32;

    const char* bG = (const char*)Wb;      // row stride 512B

    auto stageB = [&](int kcc, char* dst) {
        #pragma unroll
        for (int e = 0; e < 8; ++e) {      // 4096 x 16B = 64 KB
            int u = e * 512 + tid;
            int row = u >> 3, slot = (u & 7) << 4;
            __builtin_amdgcn_global_load_lds(
                (const __attribute__((address_space(1))) void*)(bG + (size_t)row * 512 + kcc * 128 + (slot ^ ((row & 7) << 4))),
                (__attribute__((address_space(3))) void*)(dst + row * 128 + slot), 16, 0, 0);
        }
    };

    // ---- prologue: issue Bs chunk 0; prefetch A-frags, c_in, bias into registers ----
    stageB(0, Bs0);

    const short* xr = (const short*)xh + (size_t)(n0 + wrow * 16 + (lane & 15)) * 256 + ((lane >> 4) << 3);
    bf16x8 av[8];
    #pragma unroll
    for (int z = 0; z < 8; ++z) av[z] = *(const bf16x8*)(xr + z * 32);   // K = z*32..z*32+31

    float cv[2][4];
    float bi[2], bff[2], bgg[2], boo[2];
    #pragma unroll
    for (int b = 0; b < 2; ++b) {
        int hg = (2 * wcol + b) * 16 + (lane & 15);
        bi[b]  = bias[hg];
        bff[b] = bias[128 + hg];
        bgg[b] = bias[256 + hg];
        boo[b] = bias[384 + hg];
        #pragma unroll
        for (int r = 0; r < 4; ++r) {
            int ml = wrow * 16 + ((lane >> 4) << 2) + r;
            cv[b][r] = c_in[(size_t)(n0 + ml) * H_DIM + hg];
        }
    }
    __syncthreads();                       // Bs0 staged (implicit vmcnt drain)

    // ---- K-loop: ping-pong Bs, stage(k+1) issued before MFMA(k), 1 barrier/chunk ----
    f32x4 acc[8] = {};                     // [ni] over 128 cols of this wave

    #pragma unroll
    for (int kc = 0; kc < 4; ++kc) {
        if (kc < 3) {
            stageB(kc + 1, (kc & 1) ? Bs0 : Bs1);
        } else {
            // stage head weights into retired Bs0 region (Bs0 last read in kc2)
            const char* hiG = (const char*)Wohi;
            const char* loG = (const char*)Wolo;
            const char* wrG = (const char*)Wr;
            #pragma unroll
            for (int e = 0; e < 2; ++e) {
                int u = e * 512 + tid;
                int row = u >> 4, slot = (u & 15) << 4;
                int src = row * 256 + (slot ^ ((row & 7) << 4));
                __builtin_amdgcn_global_load_lds(
                    (const __attribute__((address_space(1))) void*)(hiG + src),
                    (__attribute__((address_space(3))) void*)(Whi + row * 256 + slot), 16, 0, 0);
                __builtin_amdgcn_global_load_lds(
                    (const __attribute__((address_space(1))) void*)(loG + src),
                    (__attribute__((address_space(3))) void*)(Wlo + row * 256 + slot), 16, 0, 0);
            }
            if (tid < 256) {
                int row = tid >> 4, slot = (tid & 15) << 4;
                __builtin_amdgcn_global_load_lds(
                    (const __attribute__((address_space(1))) void*)(wrG + row * 256 + (slot ^ ((row & 7) << 4))),
                    (__attribute__((address_space(3))) void*)(Wrl + row * 256 + slot), 16, 0, 0);
            }
        }

        const char* B = (kc & 1) ? Bs1 : Bs0;
        #pragma unroll
        for (int ks = 0; ks < 2; ++ks) {
            int kb = ks * 64 + ((lane >> 4) << 4);
            #pragma unroll
            for (int ni = 0; ni < 8; ++ni) {
                int brow = wcol * 128 + ni * 16 + (lane & 15);
                bf16x8 bv = *(const bf16x8*)(B + brow * 128 + (kb ^ ((brow & 7) << 4)));
                acc[ni] = __builtin_amdgcn_mfma_f32_16x16x32_bf16(av[kc * 2 + ks], bv, acc[ni], 0, 0, 0);
            }
        }
        __syncthreads();                   // drains stage issued this iter; orders buffer reuse
    }

    // ---- LSTM pointwise in-register; h -> LDS (bf16, swizzled) ----
    #pragma unroll
    for (int b = 0; b < 2; ++b) {
        int hg = (2 * wcol + b) * 16 + (lane & 15);
        #pragma unroll
        for (int r = 0; r < 4; ++r) {
            int ml = wrow * 16 + ((lane >> 4) << 2) + r;
            float ig = acc[b * 4 + 0][r] + bi[b];
            float fg = acc[b * 4 + 1][r] + bff[b];
            float gg = acc[b * 4 + 2][r] + bgg[b];
            float og = acc[b * 4 + 3][r] + boo[b];
            float si = 1.0f / (1.0f + expf(-ig));
            float sf = 1.0f / (1.0f + expf(-fg));
            float so = 1.0f / (1.0f + expf(-og));
            float hn = so * tanhf(sf * cv[b][r] + si * tanhf(gg));
            *(short*)(Hl + ml * 256 + ((hg * 2) ^ ((ml & 7) << 4))) = f2bf(hn);
        }
    }
    __syncthreads();

    // ---- head GEMMs: out = h @ W_out (hi+lo), roleT = Wr @ h^T ----
    const int rb = wid >> 2, db2 = wid & 3;
    f32x4 oacc = {};
    f32x4 racc = {};
    #pragma unroll
    for (int ks = 0; ks < 4; ++ks) {       // K = 128
        int kb = ks * 64 + ((lane >> 4) << 4);
        int hrow = rb * 16 + (lane & 15);
        bf16x8 hv = *(const bf16x8*)(Hl + hrow * 256 + (kb ^ ((hrow & 7) << 4)));
        int drow = db2 * 16 + (lane & 15);
        int woff = drow * 256 + (kb ^ ((drow & 7) << 4));
        bf16x8 whi = *(const bf16x8*)(Whi + woff);
        bf16x8 wlo = *(const bf16x8*)(Wlo + woff);
        oacc = __builtin_amdgcn_mfma_f32_16x16x32_bf16(hv, whi, oacc, 0, 0, 0);
        oacc = __builtin_amdgcn_mfma_f32_16x16x32_bf16(hv, wlo, oacc, 0, 0, 0);
        if (db2 == 3) {
            int rrow = lane & 15;
            bf16x8 wr = *(const bf16x8*)(Wrl + rrow * 256 + (kb ^ ((rrow & 7) << 4)));
            racc = __builtin_amdgcn_mfma_f32_16x16x32_bf16(wr, hv, racc, 0, 0, 0);
        }
    }
    #pragma unroll
    for (int r = 0; r < 4; ++r) {
        int m = n0 + rb * 16 + ((lane >> 4) << 2) + r;
        out[(size_t)m * D_DIM + db2 * 16 + (lane & 15)] = oacc[r];
    }
    if (db2 == 3 && lane < 16) {
        int m = n0 + rb * 16 + lane;
        float l0 = racc[0], l1 = racc[1], l2 = racc[2];
        float mx = fmaxf(l0, fmaxf(l1, l2));
        float e0 = expf(l0 - mx), e1 = expf(l1 - mx), e2 = expf(l2 - mx);
        float s = e0 + e1 + e2;
        float* ro = out + (size_t)N_CELLS * D_DIM + (size_t)m * 3;
        ro[0] = e0 / s; ro[1] = e1 / s; ro[2] = e2 / s;
    }
}

// ---------------- host launcher: 4 dispatches, minimal critical path ----------------
extern "C" void kernel_launch(void* const* d_in, const int* in_sizes, int n_in,
                              void* d_out, int out_size, void* d_ws, size_t ws_size,
                              hipStream_t stream) {
    const int*   positions = (const int*)d_in[0];
    const float* states    = (const float*)d_in[1];
    const float* h         = (const float*)d_in[2];
    const float* c         = (const float*)d_in[3];
    const float* Wih       = (const float*)d_in[4];
    const float* Whh       = (const float*)d_in[5];
    const float* bias      = (const float*)d_in[6];
    const float* Wout      = (const float*)d_in[7];
    const float* Wrole     = (const float*)d_in[8];
    float* out             = (float*)d_out;

    char* ws = (char*)d_ws;
    int*            counts  = (int*)ws;                          // 256 KB @ 0
    int*            buckets = (int*)(ws + 262144);               // 4 MB
    __hip_bfloat16* xh      = (__hip_bfloat16*)(ws + 4456448);   // 4 MB   [8192,256] bf16
    __hip_bfloat16* Wb      = (__hip_bfloat16*)(ws + 8650752);   // 256 KB [512,256] bf16
    __hip_bfloat16* Wohi    = (__hip_bfloat16*)(ws + 8912896);   // 16 KB  [64,128] bf16
    __hip_bfloat16* Wolo    = (__hip_bfloat16*)(ws + 8929280);   // 16 KB
    __hip_bfloat16* Wr      = (__hip_bfloat16*)(ws + 8945664);   // 4 KB   [16,128] bf16

    clear_counts<<<NBINS / 1024, 256, 0, stream>>>((int4*)counts);
    fill_pack<<<193, 256, 0, stream>>>(positions, Wih, Whh, Wout, Wrole,
                                       Wb, Wohi, Wolo, Wr, counts, buckets);
    build_xh<<<N_CELLS / 4, 256, 0, stream>>>(positions, states, h, counts, buckets, xh);
    mega<<<256, 512, 0, stream>>>(xh, Wb, bias, c, Wohi, Wolo, Wr, out);
}